// Round 3
// baseline (105.634 us; speedup 1.0000x reference)
//
#include <hip/hip_runtime.h>

#define TT 48
#define II 5
#define HID 8

typedef float float2v __attribute__((ext_vector_type(2)));

// quad_perm DPP: value from lane (quad_base | perm[lane&3])
template<int CTRL>
__device__ __forceinline__ float dppf(float v) {
    return __int_as_float(__builtin_amdgcn_update_dpp(0, __float_as_int(v), CTRL, 0xF, 0xF, true));
}
// ctrl 0xB1 = lane^1, 0x4E = lane^2, 0x1B = lane^3 (quad_perm)
// ctrl 0x141 = ROW_HALF_MIRROR = lane^7 within each 8-lane group

__device__ __forceinline__ float fexp2(float x) {
    float r; asm("v_exp_f32 %0, %1" : "=v"(r) : "v"(x)); return r;
}
__device__ __forceinline__ float frcp(float x) { return __builtin_amdgcn_rcpf(x); }
__device__ __forceinline__ float2v pkfma(float2v a, float2v b, float2v c) {
    return __builtin_elementwise_fma(a, b, c);
}
__device__ __forceinline__ float2v splat(float v) { return (float2v){v, v}; }
__device__ __forceinline__ void pin2(float2v& v) { asm("" : "+v"(v)); }

__global__ __launch_bounds__(256, 4) void lstm_fused(
    const float* __restrict__ x,
    const float* __restrict__ W_ih,
    const float* __restrict__ W_hh,
    const float* __restrict__ b_ih,
    const float* __restrict__ b_hh,
    const float* __restrict__ fc_W,
    const float* __restrict__ fc_b,
    float* __restrict__ out, int B)
{
    __shared__ __align__(16) float s_fc[TT * HID];
    const int tid = threadIdx.x;
    for (int i = tid; i < TT * HID; i += 256) s_fc[i] = fc_W[i];
    __syncthreads();

    const int gt = blockIdx.x * 256 + tid;
    const int b = gt >> 3;       // 8 threads per batch element
    const int q = gt & 7;        // owned hidden unit
    if (b >= B) return;

    const float L2E  = 1.44269504088896340736f;
    const float L2E2 = 2.0f * L2E;
    // Pre-scale: i,f,o rows by -log2(e) (sigmoid = rcp(1+exp2(s)) directly),
    // g rows by +2*log2(e) (tanh = 1-2*rcp(1+exp2(u))).
    const float sI = -L2E, sF = -L2E, sG = L2E2, sO = -L2E;

    const int r_i = q, r_f = 8 + q, r_g = 16 + q, r_o = 24 + q;

    float2v wihA[II], wihB[II], whhA[HID], whhB[HID], biasA, biasB;
    #pragma unroll
    for (int i = 0; i < II; ++i) {
        wihA[i] = (float2v){sI * W_ih[r_i * II + i], sF * W_ih[r_f * II + i]};
        wihB[i] = (float2v){sG * W_ih[r_g * II + i], sO * W_ih[r_o * II + i]};
    }
    #pragma unroll
    for (int m = 0; m < HID; ++m) {
        const int e = q ^ m;  // column order matches xor-butterfly gather
        whhA[m] = (float2v){sI * W_hh[r_i * HID + e], sF * W_hh[r_f * HID + e]};
        whhB[m] = (float2v){sG * W_hh[r_g * HID + e], sO * W_hh[r_o * HID + e]};
    }
    biasA = (float2v){sI * (b_ih[r_i] + b_hh[r_i]), sF * (b_ih[r_f] + b_hh[r_f])};
    biasB = (float2v){sG * (b_ih[r_g] + b_hh[r_g]), sO * (b_ih[r_o] + b_hh[r_o])};

    // Pin everything in VGPRs: opaque defs stop the compiler from
    // rematerializing these loads inside the t-loop (R1: VGPR=48 proved
    // it was reloading all 26 pairs every step).
    #pragma unroll
    for (int i = 0; i < II; ++i) { pin2(wihA[i]); pin2(wihB[i]); }
    #pragma unroll
    for (int m = 0; m < HID; ++m) { pin2(whhA[m]); pin2(whhB[m]); }
    pin2(biasA); pin2(biasB);

    const float* xb = x + (size_t)b * (TT * II);
    const float4* xb4 = reinterpret_cast<const float4*>(xb);

    float h = 0.f, c = 0.f, acc = 0.f;

    // x staged in 4-step blocks: 20 floats = 5 float4 per block, 12 blocks.
    float xc[20];
    #pragma unroll
    for (int k = 0; k < 5; ++k) {
        float4 v = xb4[k];
        xc[4*k] = v.x; xc[4*k+1] = v.y; xc[4*k+2] = v.z; xc[4*k+3] = v.w;
    }

    #pragma unroll 1
    for (int bi = 0; bi < 12; ++bi) {
        // prefetch next block (clamped; last iter re-reads block 11)
        const int nb = (bi < 11) ? bi + 1 : 11;
        float4 p[5];
        #pragma unroll
        for (int k = 0; k < 5; ++k) p[k] = xb4[nb * 5 + k];

        #pragma unroll
        for (int s = 0; s < 4; ++s) {
            const int t = bi * 4 + s;

            float2v gA = pkfma(wihA[0], splat(xc[s*5 + 0]), biasA);
            float2v gB = pkfma(wihB[0], splat(xc[s*5 + 0]), biasB);
            #pragma unroll
            for (int i = 1; i < II; ++i) {
                gA = pkfma(wihA[i], splat(xc[s*5 + i]), gA);
                gB = pkfma(wihB[i], splat(xc[s*5 + i]), gB);
            }

            // gather all 8 h values of the batch group: pure-VALU DPP
            const float ha1 = dppf<0xB1>(h);
            const float ha2 = dppf<0x4E>(h);
            const float ha3 = dppf<0x1B>(h);
            const float ha7 = dppf<0x141>(h);    // l^7
            const float ha6 = dppf<0x141>(ha1);  // l^1^7 = l^6
            const float ha5 = dppf<0x141>(ha2);  // l^5
            const float ha4 = dppf<0x141>(ha3);  // l^4

            gA = pkfma(whhA[0], splat(h),   gA);  gB = pkfma(whhB[0], splat(h),   gB);
            gA = pkfma(whhA[1], splat(ha1), gA);  gB = pkfma(whhB[1], splat(ha1), gB);
            gA = pkfma(whhA[2], splat(ha2), gA);  gB = pkfma(whhB[2], splat(ha2), gB);
            gA = pkfma(whhA[3], splat(ha3), gA);  gB = pkfma(whhB[3], splat(ha3), gB);
            gA = pkfma(whhA[4], splat(ha4), gA);  gB = pkfma(whhB[4], splat(ha4), gB);
            gA = pkfma(whhA[5], splat(ha5), gA);  gB = pkfma(whhB[5], splat(ha5), gB);
            gA = pkfma(whhA[6], splat(ha6), gA);  gB = pkfma(whhB[6], splat(ha6), gB);
            gA = pkfma(whhA[7], splat(ha7), gA);  gB = pkfma(whhB[7], splat(ha7), gB);

            const float si = frcp(1.0f + fexp2(gA.x));
            const float sf = frcp(1.0f + fexp2(gA.y));
            const float tg = fmaf(-2.0f, frcp(1.0f + fexp2(gB.x)), 1.0f);
            const float so = frcp(1.0f + fexp2(gB.y));

            c = fmaf(sf, c, si * tg);
            const float tc = fmaf(-2.0f, frcp(1.0f + fexp2(c * L2E2)), 1.0f);
            h = so * tc;

            acc = fmaf(h, s_fc[t * HID + q], acc);
        }

        #pragma unroll
        for (int k = 0; k < 5; ++k) {
            xc[4*k] = p[k].x; xc[4*k+1] = p[k].y; xc[4*k+2] = p[k].z; xc[4*k+3] = p[k].w;
        }
    }

    // reduce acc over the 8 lanes of this batch group (all-DPP)
    acc += dppf<0xB1>(acc);
    acc += dppf<0x4E>(acc);
    acc += dppf<0x141>(acc);
    if (q == 0) out[b] = acc + fc_b[0];
}

extern "C" void kernel_launch(void* const* d_in, const int* in_sizes, int n_in,
                              void* d_out, int out_size, void* d_ws, size_t ws_size,
                              hipStream_t stream) {
    const float* x    = (const float*)d_in[0];
    const float* W_ih = (const float*)d_in[1];
    const float* W_hh = (const float*)d_in[2];
    const float* b_ih = (const float*)d_in[3];
    const float* b_hh = (const float*)d_in[4];
    const float* fc_W = (const float*)d_in[5];
    const float* fc_b = (const float*)d_in[6];
    float* out = (float*)d_out;

    const int B = in_sizes[0] / (TT * II);
    const long long threads = (long long)B * 8;
    const int grid = (int)((threads + 255) / 256);
    lstm_fused<<<grid, 256, 0, stream>>>(x, W_ih, W_hh, b_ih, b_hh, fc_W, fc_b, out, B);
}